// Round 8
// baseline (443.553 us; speedup 1.0000x reference)
//
#include <hip/hip_runtime.h>
#include <hip/hip_bf16.h>

// Problem constants (ResNet-50 CBP head)
#define BATCH 8
#define CH    2048
#define LSP   784          // H*W = 28*28
#define KPAD  800          // pad K to 25*32 for MFMA k-steps
#define KSTEPS (KPAD/32)   // 25
#define DDIM  8192         // count-sketch dim (power of 2)
#define NCLS  200
#define NTILE 16           // 2048/128 tiles per dim
#define NPAIR 136          // NTILE*(NTILE+1)/2 symmetric tile pairs
#define NSLOT 17           // part slots per batch

typedef __bf16 bf16x8 __attribute__((ext_vector_type(8)));
typedef float  f32x4  __attribute__((ext_vector_type(4)));

#define FATOMIC(p, v) unsafeAtomicAdd((p), (v))

// fp32 -> bf16 round-to-nearest-even (bit pattern)
__device__ __forceinline__ unsigned short f2bf_rn(float f) {
    unsigned int u = __float_as_uint(f);
    unsigned int r = u + 0x7fffu + ((u >> 16) & 1u);
    return (unsigned short)(r >> 16);
}

// ---------------------------------------------------------------------------
// Kernel 1: split x into hi/lo bf16 [B,C,KPAD] (vec4).  Zero-inits part/norm/
// work-counters, seeds logits with bias.
// ---------------------------------------------------------------------------
__global__ __launch_bounds__(256) void split_kernel(
    const float* __restrict__ x,
    unsigned short* __restrict__ xhi,
    unsigned short* __restrict__ xlo,
    float* __restrict__ part, float* __restrict__ norm,
    int* __restrict__ cnt,
    const float* __restrict__ bc, float* __restrict__ out)
{
    int idx = blockIdx.x * 256 + threadIdx.x;          // vec4 index
    if (idx < NSLOT * BATCH * DDIM) part[idx] = 0.0f;
    if (idx < BATCH) { norm[idx] = 0.0f; cnt[idx] = 0; }
    if (idx < BATCH * NCLS) out[idx] = bc[idx % NCLS]; // bias-seed logits
    if (idx >= BATCH * CH * KPAD / 4) return;
    int v  = idx * 4;
    int bc_ = v / KPAD;
    int l  = v - bc_ * KPAD;                           // multiple of 4
    float4 xv = make_float4(0.f, 0.f, 0.f, 0.f);
    if (l < LSP)                                       // LSP%4==0: uniform per vec
        xv = *(const float4*)&x[(size_t)bc_ * LSP + l];
    ushort4 hv, lv;
    float f[4] = {xv.x, xv.y, xv.z, xv.w};
    unsigned short hu[4], lu[4];
#pragma unroll
    for (int i = 0; i < 4; ++i) {
        hu[i] = f2bf_rn(f[i]);
        float hf = __uint_as_float(((unsigned int)hu[i]) << 16);
        lu[i] = f2bf_rn(f[i] - hf);                    // residual, exact in fp32
    }
    hv.x = hu[0]; hv.y = hu[1]; hv.z = hu[2]; hv.w = hu[3];
    lv.x = lu[0]; lv.y = lu[1]; lv.z = lu[2]; lv.w = lu[3];
    *(ushort4*)&xhi[v] = hv;
    *(ushort4*)&xlo[v] = lv;
}

// ---------------------------------------------------------------------------
// Kernel 2: persistent, software-pipelined symmetric Gram + scatter.
// grid = 512 (all-resident, 2 blocks/CU): batch = id&7 (XCD-pinned), 64
// blocks/batch pull pairs dynamically from cnt[b].  While computing pair
// i+1's k-loop, pair i's LDS-bin scatter is drip-fed one (mi,r) group per
// k-step (switch on ks -> compile-time acc indices), using the LDS pipe's
// idle capacity during the k-loop.  Only the last pair's scatter is
// exposed.  One bins flush per block.
// ---------------------------------------------------------------------------
__device__ __forceinline__ void stage_tile(
    const unsigned short* __restrict__ src, size_t rowbase_elems,
    unsigned short* lds_tile, int wv, int lane, int k0)
{
#pragma unroll
    for (int half = 0; half < 2; ++half) {
        int ch  = wv * 2 + half;                       // 0..7 chunk of 8KB tile
        int row = ch * 16 + (lane >> 2);
        int kg  = (lane & 3) ^ ((lane >> 3) & 3);      // XOR swizzle (row>>1)&3
        const unsigned short* g = src + rowbase_elems
            + (size_t)row * KPAD + k0 + kg * 8;
        __builtin_amdgcn_global_load_lds(
            (__attribute__((address_space(1))) void*)g,
            (__attribute__((address_space(3))) void*)(lds_tile + ch * 512),
            16, 0, 0);
    }
}

// Scatter one (MI,R) group of 4 entries of ACCP into bins.  MI/R must be
// compile-time constants at each use site.  (Macro-hygiene: all locals
// suffixed and NOT named like any caller loop var.)
#define SCAT_G(MI, R, ACCP, PBUF, H1CP, S1CP, H2CP, S2CP, DIAGP) do {        \
    float4 mval_ = metaRow[PBUF][rowsel + (MI) * 16 + (R)];                  \
    const float s1rv_ = mval_.x, s2rv_ = mval_.z;                            \
    const int h1rv_ = __float_as_int(mval_.y), h2rv_ = __float_as_int(mval_.w); \
    _Pragma("unroll")                                                        \
    for (int ni_ = 0; ni_ < 4; ++ni_) {                                      \
        float gval_ = ACCP[MI][ni_][(R)];                                    \
        FATOMIC(&bins[(h1rv_ + H2CP[ni_]) & (DDIM - 1)], s1rv_ * S2CP[ni_] * gval_); \
        if (!(DIAGP))                                                        \
            FATOMIC(&bins[(H1CP[ni_] + h2rv_) & (DDIM - 1)], S1CP[ni_] * s2rv_ * gval_); \
    }                                                                        \
} while (0)

// One pair's k-loop.  Stages row meta into metaRow[BUF]; if ILV, drips the
// previous pair's scatter (reading metaRow[1-BUF], accPrev) into the k-steps.
#define RUN_PAIR(PIDX, BUF, ILV, ACC, ACCP, H1CP, S1CP, H2CP, S2CP, DIAGP,   \
                 H1C, S1C, H2C, S2C, DIAG) do {                              \
    int tM_ = 0, tN_ = 0;                                                    \
    { int i_ = (PIDX);                                                       \
      _Pragma("unroll 1")                                                    \
      for (int t_ = 0; t_ < NTILE; ++t_) {                                   \
          int cnt_ = NTILE - t_;                                             \
          if (i_ < cnt_) { tM_ = t_; tN_ = t_ + i_; break; }                 \
          i_ -= cnt_;                                                        \
      } }                                                                    \
    (DIAG) = (tM_ == tN_);                                                   \
    if (tid < 128) {                                                         \
        int c1_ = tM_ * 128 + tid;                                           \
        metaRow[BUF][tid] = make_float4(s1[c1_], __int_as_float(h1[c1_]),    \
                                        s2[c1_], __int_as_float(h2[c1_]));   \
    }                                                                        \
    { const int c2b_ = tN_ * 128 + wcol + (lane & 15);                       \
      _Pragma("unroll")                                                      \
      for (int ni_ = 0; ni_ < 4; ++ni_) {                                    \
          int c2_ = c2b_ + ni_ * 16;                                         \
          (H1C)[ni_] = h1[c2_]; (S1C)[ni_] = s1[c2_];                        \
          (H2C)[ni_] = h2[c2_]; (S2C)[ni_] = s2[c2_];                        \
      } }                                                                    \
    const size_t rbA_ = ((size_t)b * CH + (size_t)tM_ * 128) * KPAD;         \
    const size_t rbB_ = ((size_t)b * CH + (size_t)tN_ * 128) * KPAD;         \
    const unsigned short* fBhi_ = (DIAG) ? smA_hi : smB_hi;                  \
    const unsigned short* fBlo_ = (DIAG) ? smA_lo : smB_lo;                  \
    { const f32x4 zv_ = {0.0f, 0.0f, 0.0f, 0.0f};                            \
      _Pragma("unroll")                                                      \
      for (int mi_ = 0; mi_ < 4; ++mi_)                                      \
          _Pragma("unroll")                                                  \
          for (int ni_ = 0; ni_ < 4; ++ni_) (ACC)[mi_][ni_] = zv_; }         \
    for (int ks_ = 0; ks_ < KSTEPS; ++ks_) {                                 \
        const int k0_ = ks_ * 32;                                            \
        stage_tile(xhi, rbA_, smA_hi, wv, lane, k0_);                        \
        stage_tile(xlo, rbA_, smA_lo, wv, lane, k0_);                        \
        if (!(DIAG)) {                                                       \
            stage_tile(xhi, rbB_, smB_hi, wv, lane, k0_);                    \
            stage_tile(xlo, rbB_, smB_lo, wv, lane, k0_);                    \
        }                                                                    \
        __syncthreads();                                                     \
        bf16x8 ah_[4], al_[4], bh_[4], bl_[4];                               \
        _Pragma("unroll")                                                    \
        for (int i_ = 0; i_ < 4; ++i_) {                                     \
            int oa_ = (wrow + i_ * 16 + rsel) * 32 + fxor;                   \
            ah_[i_] = *(const bf16x8*)&smA_hi[oa_];                          \
            al_[i_] = *(const bf16x8*)&smA_lo[oa_];                          \
            int ob_ = (wcol + i_ * 16 + rsel) * 32 + fxor;                   \
            bh_[i_] = *(const bf16x8*)&fBhi_[ob_];                           \
            bl_[i_] = *(const bf16x8*)&fBlo_[ob_];                           \
        }                                                                    \
        _Pragma("unroll")                                                    \
        for (int mi_ = 0; mi_ < 4; ++mi_)                                    \
            _Pragma("unroll")                                                \
            for (int ni_ = 0; ni_ < 4; ++ni_) {                              \
                (ACC)[mi_][ni_] = __builtin_amdgcn_mfma_f32_16x16x32_bf16(ah_[mi_], bh_[ni_], (ACC)[mi_][ni_], 0, 0, 0); \
                (ACC)[mi_][ni_] = __builtin_amdgcn_mfma_f32_16x16x32_bf16(ah_[mi_], bl_[ni_], (ACC)[mi_][ni_], 0, 0, 0); \
                (ACC)[mi_][ni_] = __builtin_amdgcn_mfma_f32_16x16x32_bf16(al_[mi_], bh_[ni_], (ACC)[mi_][ni_], 0, 0, 0); \
            }                                                                \
        if (ILV) {                                                           \
            switch (ks_) {                                                   \
            case  0: SCAT_G(0,0, ACCP, 1-(BUF), H1CP,S1CP,H2CP,S2CP, DIAGP); break; \
            case  1: SCAT_G(0,1, ACCP, 1-(BUF), H1CP,S1CP,H2CP,S2CP, DIAGP); break; \
            case  2: SCAT_G(0,2, ACCP, 1-(BUF), H1CP,S1CP,H2CP,S2CP, DIAGP); break; \
            case  3: SCAT_G(0,3, ACCP, 1-(BUF), H1CP,S1CP,H2CP,S2CP, DIAGP); break; \
            case  4: SCAT_G(1,0, ACCP, 1-(BUF), H1CP,S1CP,H2CP,S2CP, DIAGP); break; \
            case  5: SCAT_G(1,1, ACCP, 1-(BUF), H1CP,S1CP,H2CP,S2CP, DIAGP); break; \
            case  6: SCAT_G(1,2, ACCP, 1-(BUF), H1CP,S1CP,H2CP,S2CP, DIAGP); break; \
            case  7: SCAT_G(1,3, ACCP, 1-(BUF), H1CP,S1CP,H2CP,S2CP, DIAGP); break; \
            case  8: SCAT_G(2,0, ACCP, 1-(BUF), H1CP,S1CP,H2CP,S2CP, DIAGP); break; \
            case  9: SCAT_G(2,1, ACCP, 1-(BUF), H1CP,S1CP,H2CP,S2CP, DIAGP); break; \
            case 10: SCAT_G(2,2, ACCP, 1-(BUF), H1CP,S1CP,H2CP,S2CP, DIAGP); break; \
            case 11: SCAT_G(2,3, ACCP, 1-(BUF), H1CP,S1CP,H2CP,S2CP, DIAGP); break; \
            case 12: SCAT_G(3,0, ACCP, 1-(BUF), H1CP,S1CP,H2CP,S2CP, DIAGP); break; \
            case 13: SCAT_G(3,1, ACCP, 1-(BUF), H1CP,S1CP,H2CP,S2CP, DIAGP); break; \
            case 14: SCAT_G(3,2, ACCP, 1-(BUF), H1CP,S1CP,H2CP,S2CP, DIAGP); break; \
            case 15: SCAT_G(3,3, ACCP, 1-(BUF), H1CP,S1CP,H2CP,S2CP, DIAGP); break; \
            default: break;                                                  \
            }                                                                \
        }                                                                    \
        __syncthreads();                                                     \
    }                                                                        \
} while (0)

// Full straight-line scatter of one acc (used for the last pair).
// Loop var gq_ does not collide with SCAT_G locals.
#define SCAT_ALL(ACCP, PBUF, H1CP, S1CP, H2CP, S2CP, DIAGP) do {             \
    _Pragma("unroll")                                                        \
    for (int gq_ = 0; gq_ < 16; ++gq_)                                       \
        SCAT_G(gq_ >> 2, gq_ & 3, ACCP, PBUF, H1CP, S1CP, H2CP, S2CP, DIAGP); \
} while (0)

__global__ __launch_bounds__(256, 2) void gram_scatter_kernel(
    const unsigned short* __restrict__ xhi,
    const unsigned short* __restrict__ xlo,
    const int*   __restrict__ h1, const float* __restrict__ s1,
    const int*   __restrict__ h2, const float* __restrict__ s2,
    int* __restrict__ cnt, float* __restrict__ part)
{
    __shared__ __align__(16) unsigned short smA_hi[128 * 32];
    __shared__ __align__(16) unsigned short smA_lo[128 * 32];
    __shared__ __align__(16) unsigned short smB_hi[128 * 32];
    __shared__ __align__(16) unsigned short smB_lo[128 * 32];
    __shared__ float bins[DDIM];                       // 32 KB
    __shared__ float4 metaRow[2][128];                 // 4 KB double-buffered
    __shared__ int wsel;

    const int tid  = threadIdx.x;
    const int lane = tid & 63;
    const int wv   = tid >> 6;
    const int b    = blockIdx.x & 7;   // batch == XCD (id%8 round-robin)

    for (int i = tid; i < DDIM; i += 256) bins[i] = 0.0f;

    const int wrow = (wv >> 1) * 64;
    const int wcol = (wv & 1) * 64;
    const int fxor = (((lane >> 4) ^ ((lane >> 1) & 3)) << 3);
    const int rsel = lane & 15;
    const int rowsel = wrow + ((lane >> 4) << 2);      // meta row base

    f32x4 accA[4][4], accB[4][4];
    int   h1cA[4], h2cA[4]; float s1cA[4], s2cA[4]; bool diagA = true;
    int   h1cB[4], h2cB[4]; float s1cB[4], s2cB[4]; bool diagB = true;

#define GRAB(W) do { __syncthreads();                                        \
    if (tid == 0) wsel = atomicAdd(&cnt[b], 1);                              \
    __syncthreads(); (W) = wsel; } while (0)

    int w;
    GRAB(w);
    if (w < NPAIR) {
        // first pair -> accA / buf 0 (no interleave; prev args are dummies)
        RUN_PAIR(w, 0, false, accA, accA, h1cA, s1cA, h2cA, s2cA, true,
                 h1cA, s1cA, h2cA, s2cA, diagA);
        bool lastIsA = true;
        for (;;) {
            GRAB(w);
            if (w >= NPAIR) break;
            RUN_PAIR(w, 1, true, accB, accA, h1cA, s1cA, h2cA, s2cA, diagA,
                     h1cB, s1cB, h2cB, s2cB, diagB);
            lastIsA = false;
            GRAB(w);
            if (w >= NPAIR) break;
            RUN_PAIR(w, 0, true, accA, accB, h1cB, s1cB, h2cB, s2cB, diagB,
                     h1cA, s1cA, h2cA, s2cA, diagA);
            lastIsA = true;
        }
        if (lastIsA) SCAT_ALL(accA, 0, h1cA, s1cA, h2cA, s2cA, diagA);
        else         SCAT_ALL(accB, 1, h1cB, s1cB, h2cB, s2cB, diagB);

        __syncthreads();   // all scatters into bins complete

        // Flush once per block into a part slot; rotated order decontends.
        float* pb = part + ((size_t)(((blockIdx.x >> 3) % NSLOT) * BATCH + b) * DDIM);
        const int rot = (blockIdx.x & 31) << 8;
        for (int i = tid; i < DDIM; i += 256) {
            int j = (i + rot) & (DDIM - 1);
            float v = bins[j];
            if (v != 0.0f) FATOMIC(&pb[j], v);
        }
    }
#undef GRAB
}

// ---------------------------------------------------------------------------
// Kernel 3: y[b,d] = sum over 17 part slots; accumulate norm[b] += sum|y|.
// ---------------------------------------------------------------------------
__global__ __launch_bounds__(256) void reduce_kernel(
    const float* __restrict__ part, float* __restrict__ y,
    float* __restrict__ norm)
{
    const int tid = threadIdx.x;
    const int b  = blockIdx.x >> 3;
    const int d0 = (blockIdx.x & 7) * 1024;
    float ab = 0.0f;
    for (int dd = tid; dd < 1024; dd += 256) {
        int d = d0 + dd;
        float s = 0.0f;
#pragma unroll
        for (int p = 0; p < NSLOT; ++p)
            s += part[((size_t)p * BATCH + b) * DDIM + d];
        y[(size_t)b * DDIM + d] = s;
        ab += fabsf(s);   // sum|y| == sum feat_unnorm^2
    }
    __shared__ float red[256];
    red[tid] = ab;
    __syncthreads();
    for (int s = 128; s > 0; s >>= 1) {
        if (tid < s) red[tid] += red[tid + s];
        __syncthreads();
    }
    if (tid == 0) FATOMIC(&norm[b], red[0]);
}

// ---------------------------------------------------------------------------
// Kernel 4: fused signed-sqrt + L2-normalize + classifier GEMV.
// ---------------------------------------------------------------------------
__global__ __launch_bounds__(256) void logit_kernel(
    const float* __restrict__ y, const float* __restrict__ norm,
    const float* __restrict__ W, float* __restrict__ out)
{
    const int j = blockIdx.x;
    const int tid = threadIdx.x;
    __shared__ float fs[BATCH][128];                   // 4 KB
    for (int i = tid; i < BATCH * 128; i += 256) {
        int bb = i >> 7, dd = i & 127;
        float v = y[(size_t)bb * DDIM + j * 128 + dd];
        float inv = 1.0f / fmaxf(sqrtf(norm[bb]), 1e-12f);
        float f = copysignf(sqrtf(fabsf(v)), v) * inv;
        fs[bb][dd] = f;
        out[BATCH * NCLS + (size_t)bb * DDIM + j * 128 + dd] = f;
    }
    __syncthreads();
    if (tid < NCLS) {
        float a[BATCH];
#pragma unroll
        for (int bb = 0; bb < BATCH; ++bb) a[bb] = 0.0f;
        for (int dd = 0; dd < 128; ++dd) {
            float w = W[(size_t)(j * 128 + dd) * NCLS + tid];
#pragma unroll
            for (int bb = 0; bb < BATCH; ++bb) a[bb] += fs[bb][dd] * w;
        }
#pragma unroll
        for (int bb = 0; bb < BATCH; ++bb)
            FATOMIC(&out[bb * NCLS + tid], a[bb]);
    }
}

// ---------------------------------------------------------------------------
extern "C" void kernel_launch(void* const* d_in, const int* in_sizes, int n_in,
                              void* d_out, int out_size, void* d_ws, size_t ws_size,
                              hipStream_t stream)
{
    const float* x  = (const float*)d_in[0];
    const float* s1 = (const float*)d_in[1];
    const float* s2 = (const float*)d_in[2];
    const float* W  = (const float*)d_in[3];
    const float* bc = (const float*)d_in[4];
    const int*   h1 = (const int*)d_in[5];
    const int*   h2 = (const int*)d_in[6];
    float* out = (float*)d_out;

    // ws layout: part (4.46MB) | y (256KB) | norm(128B) | cnt(128B) | xhi | xlo
    char* ws = (char*)d_ws;
    float* part = (float*)ws;
    const size_t partbytes = (size_t)NSLOT * BATCH * DDIM * sizeof(float);
    float* y    = (float*)(ws + partbytes);
    const size_t ybytes = (size_t)BATCH * DDIM * sizeof(float);
    float* norm = (float*)(ws + partbytes + ybytes);
    int*   cnt  = (int*)(ws + partbytes + ybytes + 128);
    unsigned short* xhi = (unsigned short*)(ws + partbytes + ybytes + 256);
    unsigned short* xlo = xhi + (size_t)BATCH * CH * KPAD;

    split_kernel<<<(BATCH * CH * KPAD / 4 + 255) / 256, 256, 0, stream>>>(
        x, xhi, xlo, part, norm, cnt, bc, out);

    gram_scatter_kernel<<<512, 256, 0, stream>>>(
        xhi, xlo, h1, s1, h2, s2, cnt, part);

    reduce_kernel<<<64, 256, 0, stream>>>(part, y, norm);

    logit_kernel<<<64, 256, 0, stream>>>(y, norm, W, out);
}

// Round 9
// 348.063 us; speedup vs baseline: 1.2743x; 1.2743x over previous
//
#include <hip/hip_runtime.h>
#include <hip/hip_bf16.h>

// Problem constants (ResNet-50 CBP head)
#define BATCH 8
#define CH    2048
#define LSP   784          // H*W = 28*28
#define KPAD  800          // pad K to 25*32 for MFMA k-steps
#define KSTEPS (KPAD/32)   // 25
#define DDIM  8192         // count-sketch dim (power of 2)
#define NCLS  200
#define NTILE 16           // 2048/128 tiles per dim
#define NPAIR 136          // NTILE*(NTILE+1)/2 symmetric tile pairs
#define NSLOT 68           // part slots per batch (2 blocks/slot)

typedef _Float16 f16x8 __attribute__((ext_vector_type(8)));
typedef _Float16 f16x4 __attribute__((ext_vector_type(4)));
typedef float    f32x4 __attribute__((ext_vector_type(4)));

#define FATOMIC(p, v) unsafeAtomicAdd((p), (v))

// ---------------------------------------------------------------------------
// Kernel 1: convert x (fp32 [B,C,784]) to fp16 [B,C,KPAD] (zero-pad K).
// fp16 (11-bit mantissa) keeps Gram rel-err ~1e-4 -> single MFMA, no hi/lo.
// Also zero-inits part/norm, seeds logits with bias.
// ---------------------------------------------------------------------------
__global__ __launch_bounds__(256) void split_kernel(
    const float* __restrict__ x,
    _Float16* __restrict__ xh,
    float* __restrict__ part, float* __restrict__ norm,
    const float* __restrict__ bc, float* __restrict__ out)
{
    int idx = blockIdx.x * 256 + threadIdx.x;          // vec4 index
    if (idx < NSLOT * BATCH * DDIM / 4)                // zero part (float4)
        *(float4*)&part[idx * 4] = make_float4(0.f, 0.f, 0.f, 0.f);
    if (idx < BATCH) norm[idx] = 0.0f;
    if (idx < BATCH * NCLS) out[idx] = bc[idx % NCLS]; // bias-seed logits
    if (idx >= BATCH * CH * KPAD / 4) return;
    int v  = idx * 4;
    int bc_ = v / KPAD;
    int l  = v - bc_ * KPAD;                           // multiple of 4
    float4 xv = make_float4(0.f, 0.f, 0.f, 0.f);
    if (l < LSP)                                       // LSP%4==0: uniform per vec
        xv = *(const float4*)&x[(size_t)bc_ * LSP + l];
    f16x4 hv;
    hv[0] = (_Float16)xv.x; hv[1] = (_Float16)xv.y;
    hv[2] = (_Float16)xv.z; hv[3] = (_Float16)xv.w;
    *(f16x4*)&xh[v] = hv;
}

// ---------------------------------------------------------------------------
// Kernel 2: symmetric Gram tile (fp16 MFMA) + count-sketch scatter.
// grid = 1088: batch = id&7 (one batch per XCD, 3.3 MB L2 set), pair = id>>3.
// LDS 50 KB (smA 8 + smB 8 + bins 32 + meta 2) -> 3 blocks/CU: cross-block
// phase overlap hides part of the ds_add scatter behind other blocks' k-loops
// (R8 showed in-block interleave can't: atomics and ds_read share the pipe).
// ---------------------------------------------------------------------------
__device__ __forceinline__ void stage_tile(
    const _Float16* __restrict__ src, size_t rowbase_elems,
    unsigned short* lds_tile, int wv, int lane, int k0)
{
#pragma unroll
    for (int half = 0; half < 2; ++half) {
        int ch  = wv * 2 + half;                       // 0..7 chunk of 8KB tile
        int row = ch * 16 + (lane >> 2);
        int kg  = (lane & 3) ^ ((lane >> 3) & 3);      // XOR swizzle (row>>1)&3
        const _Float16* g = src + rowbase_elems
            + (size_t)row * KPAD + k0 + kg * 8;
        __builtin_amdgcn_global_load_lds(
            (__attribute__((address_space(1))) void*)g,
            (__attribute__((address_space(3))) void*)(lds_tile + ch * 512),
            16, 0, 0);
    }
}

__global__ __launch_bounds__(256, 3) void gram_scatter_kernel(
    const _Float16* __restrict__ xh,
    const int*   __restrict__ h1, const float* __restrict__ s1,
    const int*   __restrict__ h2, const float* __restrict__ s2,
    float* __restrict__ part)
{
    __shared__ __align__(16) unsigned short smA[128 * 32];   // 8 KB fp16 tile
    __shared__ __align__(16) unsigned short smB[128 * 32];   // 8 KB
    __shared__ float bins[DDIM];                             // 32 KB
    __shared__ float4 metaA[128];                            // 2 KB

    const int tid  = threadIdx.x;
    const int lane = tid & 63;
    const int wv   = tid >> 6;
    const int b    = blockIdx.x & 7;       // batch in low bits -> one batch/XCD
    const int pidx = blockIdx.x >> 3;      // triangular pair index

    // Triangular decode: pidx in [0,136) -> (tM, tN), tM <= tN, row-major
    int tM = 0, tN = 0;
    {
        int i = pidx;
#pragma unroll 1
        for (int t = 0; t < NTILE; ++t) {
            int cnt = NTILE - t;
            if (i < cnt) { tM = t; tN = t + i; break; }
            i -= cnt;
        }
    }
    const bool diag = (tM == tN);

    for (int i = tid; i < DDIM; i += 256) bins[i] = 0.0f;
    // (first __syncthreads inside k-loop orders this before any scatter)

    const int wrow = (wv >> 1) * 64;    // wave's 64x64 subtile origin
    const int wcol = (wv & 1) * 64;

    const size_t rowbaseA = ((size_t)b * CH + (size_t)tM * 128) * KPAD;
    const size_t rowbaseB = ((size_t)b * CH + (size_t)tN * 128) * KPAD;

    const unsigned short* fragB = diag ? smA : smB;

    f32x4 acc[4][4];
    const f32x4 zv = {0.0f, 0.0f, 0.0f, 0.0f};
#pragma unroll
    for (int mi = 0; mi < 4; ++mi)
#pragma unroll
        for (int ni = 0; ni < 4; ++ni) acc[mi][ni] = zv;

    // fragment LDS offset: (row)*32 + fxor; XOR term is a per-lane constant
    const int fxor = (((lane >> 4) ^ ((lane >> 1) & 3)) << 3);
    const int rsel = lane & 15;

    for (int ks = 0; ks < KSTEPS; ++ks) {
        const int k0 = ks * 32;
        stage_tile(xh, rowbaseA, smA, wv, lane, k0);
        if (!diag) stage_tile(xh, rowbaseB, smB, wv, lane, k0);
        __syncthreads();

        f16x8 ah[4], bh[4];
#pragma unroll
        for (int i = 0; i < 4; ++i) {
            int offa = (wrow + i * 16 + rsel) * 32 + fxor;
            ah[i] = *(const f16x8*)&smA[offa];
            int offb = (wcol + i * 16 + rsel) * 32 + fxor;
            bh[i] = *(const f16x8*)&fragB[offb];
        }
#pragma unroll
        for (int mi = 0; mi < 4; ++mi)
#pragma unroll
            for (int ni = 0; ni < 4; ++ni)
                acc[mi][ni] = __builtin_amdgcn_mfma_f32_16x16x32_f16(ah[mi], bh[ni], acc[mi][ni], 0, 0, 0);
        __syncthreads();
    }

    // Stage scatter meta for this tile's 128 c1-rows into LDS.
    if (tid < 128) {
        int c1 = tM * 128 + tid;
        metaA[tid] = make_float4(s1[c1], __int_as_float(h1[c1]),
                                 s2[c1], __int_as_float(h2[c1]));
    }
    __syncthreads();

    // Scatter the 128x128 Gram tile into the LDS histogram.
    // C/D layout (m89-verified): col = lane&15, row = (lane>>4)*4 + reg
    // Off-diagonal pair: each entry contributes twice (G symmetric).
    const int c2b = tN * 128 + wcol + (lane & 15);
    const int rowsel = wrow + ((lane >> 4) << 2);
    int   h1c[4], h2c[4]; float s1c[4], s2c[4];
#pragma unroll
    for (int ni = 0; ni < 4; ++ni) {
        int c2 = c2b + ni * 16;
        h1c[ni] = h1[c2]; s1c[ni] = s1[c2];
        h2c[ni] = h2[c2]; s2c[ni] = s2[c2];
    }
#pragma unroll
    for (int mi = 0; mi < 4; ++mi) {
#pragma unroll
        for (int r = 0; r < 4; ++r) {
            float4 m = metaA[rowsel + mi * 16 + r];    // one ds_read_b128
            const float s1r = m.x, s2r = m.z;
            const int h1r = __float_as_int(m.y);
            const int h2r = __float_as_int(m.w);
#pragma unroll
            for (int ni = 0; ni < 4; ++ni) {
                float g = acc[mi][ni][r];
                FATOMIC(&bins[(h1r + h2c[ni]) & (DDIM - 1)], s1r * s2c[ni] * g);
                if (!diag)
                    FATOMIC(&bins[(h1c[ni] + h2r) & (DDIM - 1)], s1c[ni] * s2r * g);
            }
        }
    }

    __syncthreads();   // all scatters into bins complete

    // Flush to one of 68 part slots (2 blocks/slot -> near-uncontended),
    // rotated start per block to decontend cache lines.
    float* pb = part + ((size_t)((pidx % NSLOT) * BATCH + b) * DDIM);
    const int rot = (blockIdx.x & 31) << 8;
    for (int i = tid; i < DDIM; i += 256) {
        int j = (i + rot) & (DDIM - 1);
        float v = bins[j];
        if (v != 0.0f) FATOMIC(&pb[j], v);
    }
}

// ---------------------------------------------------------------------------
// Kernel 3: y[b,d] = sum over 68 part slots; accumulate norm[b] += sum|y|.
// grid 64 x 256: one float4 of d per thread.
// ---------------------------------------------------------------------------
__global__ __launch_bounds__(256) void reduce_kernel(
    const float* __restrict__ part, float* __restrict__ y,
    float* __restrict__ norm)
{
    const int tid = threadIdx.x;
    const int b  = blockIdx.x >> 3;
    const int d0 = (((blockIdx.x & 7) * 256) + tid) * 4;   // float4 slice
    float4 s = make_float4(0.f, 0.f, 0.f, 0.f);
#pragma unroll 4
    for (int p = 0; p < NSLOT; ++p) {
        float4 v = *(const float4*)&part[((size_t)p * BATCH + b) * DDIM + d0];
        s.x += v.x; s.y += v.y; s.z += v.z; s.w += v.w;
    }
    *(float4*)&y[(size_t)b * DDIM + d0] = s;
    float ab = fabsf(s.x) + fabsf(s.y) + fabsf(s.z) + fabsf(s.w);
    __shared__ float red[256];
    red[tid] = ab;
    __syncthreads();
    for (int st = 128; st > 0; st >>= 1) {
        if (tid < st) red[tid] += red[tid + st];
        __syncthreads();
    }
    if (tid == 0) FATOMIC(&norm[b], red[0]);   // sum|y| == sum feat_unnorm^2
}

// ---------------------------------------------------------------------------
// Kernel 4: fused signed-sqrt + L2-normalize + classifier GEMV.
// grid 64: block j owns d in [128j, 128j+128) for all batches.
// ---------------------------------------------------------------------------
__global__ __launch_bounds__(256) void logit_kernel(
    const float* __restrict__ y, const float* __restrict__ norm,
    const float* __restrict__ W, float* __restrict__ out)
{
    const int j = blockIdx.x;
    const int tid = threadIdx.x;
    __shared__ float fs[BATCH][128];                   // 4 KB
    for (int i = tid; i < BATCH * 128; i += 256) {
        int bb = i >> 7, dd = i & 127;
        float v = y[(size_t)bb * DDIM + j * 128 + dd];
        float inv = 1.0f / fmaxf(sqrtf(norm[bb]), 1e-12f);
        float f = copysignf(sqrtf(fabsf(v)), v) * inv;
        fs[bb][dd] = f;
        out[BATCH * NCLS + (size_t)bb * DDIM + j * 128 + dd] = f;
    }
    __syncthreads();
    if (tid < NCLS) {
        float a[BATCH];
#pragma unroll
        for (int bb = 0; bb < BATCH; ++bb) a[bb] = 0.0f;
        for (int dd = 0; dd < 128; ++dd) {
            float w = W[(size_t)(j * 128 + dd) * NCLS + tid];
#pragma unroll
            for (int bb = 0; bb < BATCH; ++bb) a[bb] += fs[bb][dd] * w;
        }
#pragma unroll
        for (int bb = 0; bb < BATCH; ++bb)
            FATOMIC(&out[bb * NCLS + tid], a[bb]);
    }
}

// ---------------------------------------------------------------------------
extern "C" void kernel_launch(void* const* d_in, const int* in_sizes, int n_in,
                              void* d_out, int out_size, void* d_ws, size_t ws_size,
                              hipStream_t stream)
{
    const float* x  = (const float*)d_in[0];
    const float* s1 = (const float*)d_in[1];
    const float* s2 = (const float*)d_in[2];
    const float* W  = (const float*)d_in[3];
    const float* bc = (const float*)d_in[4];
    const int*   h1 = (const int*)d_in[5];
    const int*   h2 = (const int*)d_in[6];
    float* out = (float*)d_out;

    // ws layout: part (17.8MB) | y (256KB) | norm (128B) | xh (26.2MB) ~ 44.3MB
    char* ws = (char*)d_ws;
    float* part = (float*)ws;
    const size_t partbytes = (size_t)NSLOT * BATCH * DDIM * sizeof(float);
    float* y    = (float*)(ws + partbytes);
    const size_t ybytes = (size_t)BATCH * DDIM * sizeof(float);
    float* norm = (float*)(ws + partbytes + ybytes);
    _Float16* xh = (_Float16*)(ws + partbytes + ybytes + 128);

    split_kernel<<<(BATCH * CH * KPAD / 4 + 255) / 256, 256, 0, stream>>>(
        x, xh, part, norm, bc, out);

    gram_scatter_kernel<<<NPAIR * BATCH, 256, 0, stream>>>(
        xh, h1, s1, h2, s2, part);

    reduce_kernel<<<64, 256, 0, stream>>>(part, y, norm);

    logit_kernel<<<64, 256, 0, stream>>>(y, norm, W, out);
}